// Round 6
// baseline (426.648 us; speedup 1.0000x reference)
//
#include <hip/hip_runtime.h>
#include <stdint.h>

typedef int v4i __attribute__((ext_vector_type(4)));
typedef int v16i __attribute__((ext_vector_type(16)));

__device__ __forceinline__ int clamp_i8(int v) {
    return v < -128 ? -128 : (v > 127 ? 127 : v);
}

__device__ __forceinline__ void async_load16(const void* g, void* l) {
    __builtin_amdgcn_global_load_lds(
        (const __attribute__((address_space(1))) void*)g,
        (__attribute__((address_space(3))) void*)l, 16, 0, 0);
}

// ---------------- pre-pass 1: quantize fp32 input -> int8 -------------------
__global__ void quant_input_kernel(const float4* __restrict__ x, int* __restrict__ q,
                                   const float* __restrict__ scale_p,
                                   const int* __restrict__ zp_p, int n4) {
    const float inv = 1.0f / *scale_p;
    const int zp = *zp_p;
    const int stride = gridDim.x * blockDim.x;
    for (int t = blockIdx.x * blockDim.x + threadIdx.x; t < n4; t += stride) {
        float4 v = x[t];
        int q0 = clamp_i8((int)rintf(v.x * inv) + zp);
        int q1 = clamp_i8((int)rintf(v.y * inv) + zp);
        int q2 = clamp_i8((int)rintf(v.z * inv) + zp);
        int q3 = clamp_i8((int)rintf(v.w * inv) + zp);
        q[t] = (q0 & 255) | ((q1 & 255) << 8) | ((q2 & 255) << 16) | ((q3 & 255) << 24);
    }
}

// ---------------- pre-pass 2: pack int32 weight -> int8 ---------------------
__global__ void pack_weight_kernel(const int4* __restrict__ w, int* __restrict__ q, int n4) {
    const int stride = gridDim.x * blockDim.x;
    for (int t = blockIdx.x * blockDim.x + threadIdx.x; t < n4; t += stride) {
        int4 v = w[t];
        q[t] = (v.x & 255) | ((v.y & 255) << 8) | ((v.z & 255) << 16) | ((v.w & 255) << 24);
    }
}

// ---------------- main GEMM: C[i][j] = sum_k A[i][k] * W[j][k] ----------------
// ROUND 6: fine-grained phase template (T3+T4+T5, guide m201 pattern) for i8.
// 512 threads / 8 waves (2Mx4N), block 256x256, BK=64, wave tile 128x64
// (4x2 of 32x32x32 -> acc 128 regs -> ~230/wave -> 2 waves/SIMD).
// LDS: 4 K-tile slots (lA[2][2], lB[2][2]) = 128 KB, template-verified size.
// Iteration = 2 K-tiles (pair cur), 4 phases; each phase:
//   {6 ds_read (this phase's frags); 2 global_load_lds (one half-tile pair);
//    s_barrier; lgkmcnt(0); setprio(1); 8 MFMA; setprio(0);
//    [vmcnt(4) at phases 2,4]; s_barrier}
// Counted vmcnt NEVER drains the newest 4 loads (the 2 half-pairs still in
// flight) -> loads span phases, unlike R1's full drain. All slot indices are
// compile-time (R3/R4 lesson: runtime indices -> selects/spills).
// Residency invariants (per-wave outstanding global_load_lds, 2/stage-point):
//  - end ph4 VMC4 -> this iter's ph1,ph2 (= tile 2i+2 A,B) landed before the
//    next iter's ph1/ph2 reads of slot [oth][0].
//  - end ph2 VMC4 -> prev iter's ph3,ph4 (= tile 2i+1 A,B) landed before
//    ph3/ph4 reads of slot [cur][1].
//  - WAR: any stage into a slot is >=1 barrier after ALL waves' last reads of
//    it (per-wave lgkmcnt(0) before each MFMA cluster + shared barriers).
#define BM 256
#define BN 256
#define BK 64

__global__ __launch_bounds__(512, 1) void gemm_i8_kernel(
    const int8_t* __restrict__ A, const int8_t* __restrict__ W,
    const int* __restrict__ bias, int* __restrict__ C,
    const float* __restrict__ oscale_p, const int* __restrict__ ozp_p,
    int N, int K, int M) {
    __shared__ int8_t lA[2][2][BM * BK];  // [pair][sub] 4 x 16 KiB
    __shared__ int8_t lB[2][2][BN * BK];  // [pair][sub] 4 x 16 KiB  (128 KiB)

    const int tid = threadIdx.x;
    const int lane = tid & 63;
    const int w = tid >> 6;   // wave 0..7
    const int wm = w >> 2;    // wave row (0..1) -> tile rows wm*128
    const int wn = w & 3;     // wave col (0..3) -> tile cols wn*64

    const int bm = blockIdx.y * BM;
    const int bn = blockIdx.x * BN;

    // --- staging: thread t covers tile row (t>>2) of a 128-row half.
    // lane l -> LDS row base + (l>>2), physical chunk l&3; source chunk is
    // pre-swizzled: (l&3) ^ ((row>>1)&3)  [verified R1 swizzle, w*16 and
    // h*128 offsets are 0 mod 4 after >>1 so the formula is unchanged]
    const int s_sub = lane >> 2;                                  // 0..15
    const int s_col = ((lane & 3) ^ ((s_sub >> 1) & 3)) * 16;
    const int8_t* gA = A + (int64_t)(bm + w * 16 + s_sub) * K + s_col;
    const int8_t* gB = W + (int64_t)(bn + w * 16 + s_sub) * K + s_col;
    const int64_t hstep = (int64_t)128 * K;   // +128 rows (second half)

    // --- fragment identities (A/B: [m=lane&31][k=(lane>>5)*16+j])
    const int m0 = lane & 31;
    const int rsw = (m0 >> 1) & 3;   // row-swizzle term
    const int chi = lane >> 5;       // k-half chunk contribution

    v16i acc[4][2];
#pragma unroll
    for (int i = 0; i < 4; i++)
#pragma unroll
        for (int j = 0; j < 2; j++)
#pragma unroll
            for (int r = 0; r < 16; r++) acc[i][j][r] = 0;

#define STAGE_A(p, s, koff)                                     \
    do {                                                        \
        async_load16(gA + (koff), &lA[p][s][w * 1024]);         \
        async_load16(gA + hstep + (koff), &lA[p][s][8192 + w * 1024]); \
    } while (0)
#define STAGE_B(p, s, koff)                                     \
    do {                                                        \
        async_load16(gB + (koff), &lB[p][s][w * 1024]);         \
        async_load16(gB + hstep + (koff), &lB[p][s][8192 + w * 1024]); \
    } while (0)
#define VMC4 asm volatile("s_waitcnt vmcnt(4)" ::: "memory")
#define VMC0 asm volatile("s_waitcnt vmcnt(0)" ::: "memory")
#define VNOP do {} while (0)

#define PHASE(p, s, k0, SG, VM)                                               \
    do {                                                                      \
        const int8_t* cA_ = lA[p][s];                                         \
        const int8_t* cB_ = lB[p][s];                                         \
        const int cc_ = (((((k0) >> 4) + chi)) ^ rsw) << 4;                   \
        v4i af_[4], bf_[2];                                                   \
        _Pragma("unroll") for (int ms = 0; ms < 4; ms++)                      \
            af_[ms] = *(const v4i*)&cA_[(wm * 128 + ms * 32 + m0) * BK + cc_];\
        _Pragma("unroll") for (int ns = 0; ns < 2; ns++)                      \
            bf_[ns] = *(const v4i*)&cB_[(wn * 64 + ns * 32 + m0) * BK + cc_]; \
        SG;                                                                   \
        __builtin_amdgcn_s_barrier();                                         \
        asm volatile("s_waitcnt lgkmcnt(0)" ::: "memory");                    \
        __builtin_amdgcn_s_setprio(1);                                        \
        _Pragma("unroll") for (int ms = 0; ms < 4; ms++)                      \
            _Pragma("unroll") for (int ns = 0; ns < 2; ns++)                  \
                acc[ms][ns] = __builtin_amdgcn_mfma_i32_32x32x32_i8(          \
                    af_[ms], bf_[ns], acc[ms][ns], 0, 0, 0);                  \
        __builtin_amdgcn_s_setprio(0);                                        \
        VM;                                                                   \
        __builtin_amdgcn_s_barrier();                                         \
    } while (0)

// Iteration i: compute K-tiles {2i,2i+1} from pair cur; stage {2i+2,2i+3}
// into pair oth. gA/gB advance 128 k-bytes per iteration (static adds).
#define ITER(cur, oth)                                     \
    do {                                                   \
        PHASE(cur, 0, 0,  STAGE_A(oth, 0, 0),  VNOP);      \
        PHASE(cur, 0, 32, STAGE_B(oth, 0, 0),  VMC4);      \
        PHASE(cur, 1, 0,  STAGE_A(oth, 1, 64), VNOP);      \
        PHASE(cur, 1, 32, STAGE_B(oth, 1, 64), VMC4);      \
        gA += 128;                                         \
        gB += 128;                                         \
    } while (0)

#define LASTI(cur)                           \
    do {                                     \
        PHASE(cur, 0, 0,  VNOP, VNOP);       \
        PHASE(cur, 0, 32, VNOP, VMC0);       \
        PHASE(cur, 1, 0,  VNOP, VNOP);       \
        PHASE(cur, 1, 32, VNOP, VNOP);       \
    } while (0)

    // prologue: stage K-tiles 0,1 into pair 0 (8 loads/wave in flight)
    STAGE_A(0, 0, 0);
    STAGE_B(0, 0, 0);
    STAGE_A(0, 1, 64);
    STAGE_B(0, 1, 64);
    gA += 128;
    gB += 128;
    VMC4;  // tile 0 (first 4 loads) landed; tile 1's 4 may remain in flight
    __builtin_amdgcn_s_barrier();

    const int nPairs = (K / 128) - 1;  // staging iterations (31 for K=4096)
    if (nPairs & 1) {
        for (int i = 0; i < nPairs / 2; ++i) {
            ITER(0, 1);
            ITER(1, 0);
        }
        ITER(0, 1);
        LASTI(1);
    } else {
        for (int i = 0; i < nPairs / 2; ++i) {
            ITER(0, 1);
            ITER(1, 0);
        }
        LASTI(0);
    }

#undef ITER
#undef LASTI
#undef PHASE
#undef STAGE_A
#undef STAGE_B
#undef VMC4
#undef VMC0
#undef VNOP

    // --- epilogue: requantize, store int32
    // C/D layout (32x32): col = lane&31, row = (reg&3) + 8*(reg>>2) + 4*(lane>>5)
    const float inv_os = 1.0f / *oscale_p;
    const int ozp = *ozp_p;
    const int rbase = 4 * (lane >> 5);
#pragma unroll
    for (int ns = 0; ns < 2; ns++) {
        const int gn = bn + wn * 64 + ns * 32 + m0;
        const int bv = bias[gn];
#pragma unroll
        for (int ms = 0; ms < 4; ms++) {
            const int gm0 = bm + wm * 128 + ms * 32 + rbase;
            v16i a = acc[ms][ns];
#pragma unroll
            for (int reg = 0; reg < 16; reg++) {
                const int row = (reg & 3) + 8 * (reg >> 2);
                int v = a[reg] + bv;
                int q = (int)rintf((float)v * inv_os) + ozp;
                q = clamp_i8(q);
                C[(int64_t)(gm0 + row) * M + gn] = q;
            }
        }
    }
}

extern "C" void kernel_launch(void* const* d_in, const int* in_sizes, int n_in,
                              void* d_out, int out_size, void* d_ws, size_t ws_size,
                              hipStream_t stream) {
    const float* x = (const float*)d_in[0];
    const int* wgt = (const int*)d_in[1];
    const int* bias = (const int*)d_in[2];
    const float* in_scale = (const float*)d_in[3];
    const int* in_zp = (const int*)d_in[4];
    const float* out_scale = (const float*)d_in[5];
    const int* out_zp = (const int*)d_in[6];

    const int64_t x_elems = (int64_t)in_sizes[0];  // N*K
    const int OUT = in_sizes[2];                   // bias length
    const int K = in_sizes[1] / OUT;               // IN
    const int N = (int)(x_elems / K);

    int8_t* qA = (int8_t*)d_ws;
    int8_t* qW = qA + x_elems;

    {
        int n4 = (int)(x_elems / 4);               // 8.4M float4s
        quant_input_kernel<<<4096, 256, 0, stream>>>(
            (const float4*)x, (int*)qA, in_scale, in_zp, n4);
    }
    {
        int n4 = (int)(((int64_t)OUT * K) / 4);    // 4.2M int4s
        pack_weight_kernel<<<2048, 256, 0, stream>>>(
            (const int4*)wgt, (int*)qW, n4);
    }
    dim3 grid(OUT / BN, N / BM);
    gemm_i8_kernel<<<grid, 512, 0, stream>>>(qA, qW, bias, (int*)d_out,
                                             out_scale, out_zp, N, K, OUT);
}

// Round 7
// 425.102 us; speedup vs baseline: 1.0036x; 1.0036x over previous
//
#include <hip/hip_runtime.h>
#include <stdint.h>

typedef int v4i __attribute__((ext_vector_type(4)));
typedef int v16i __attribute__((ext_vector_type(16)));

__device__ __forceinline__ int clamp_i8(int v) {
    return v < -128 ? -128 : (v > 127 ? 127 : v);
}

__device__ __forceinline__ void async_load16(const void* g, void* l) {
    __builtin_amdgcn_global_load_lds(
        (const __attribute__((address_space(1))) void*)g,
        (__attribute__((address_space(3))) void*)l, 16, 0, 0);
}

// ---------------- pre-pass 1: quantize fp32 input -> int8 -------------------
__global__ void quant_input_kernel(const float4* __restrict__ x, int* __restrict__ q,
                                   const float* __restrict__ scale_p,
                                   const int* __restrict__ zp_p, int n4) {
    const float inv = 1.0f / *scale_p;
    const int zp = *zp_p;
    const int stride = gridDim.x * blockDim.x;
    for (int t = blockIdx.x * blockDim.x + threadIdx.x; t < n4; t += stride) {
        float4 v = x[t];
        int q0 = clamp_i8((int)rintf(v.x * inv) + zp);
        int q1 = clamp_i8((int)rintf(v.y * inv) + zp);
        int q2 = clamp_i8((int)rintf(v.z * inv) + zp);
        int q3 = clamp_i8((int)rintf(v.w * inv) + zp);
        q[t] = (q0 & 255) | ((q1 & 255) << 8) | ((q2 & 255) << 16) | ((q3 & 255) << 24);
    }
}

// ---------------- pre-pass 2: pack int32 weight -> int8 B-FRAGMENTS ---------
// Fragment-order layout so the GEMM can load B operands global->register with
// lane-contiguous 1KB bursts (B leaves the LDS pipe entirely):
//   fragment t = ((c32 * (K/32) + k32) * 64 + lane), 16 bytes each, where
//   col = c32*32 + (lane&31), k = k32*32 + (lane>>5)*16 + 0..15
// This matches the mfma_i32_32x32x32_i8 B-operand identity
// [col = lane&31][k = (lane>>5)*16 + j] exactly (verified R1 mapping).
__global__ void pack_weight_kernel(const int* __restrict__ w, int4* __restrict__ q,
                                   int K, int nfrag) {
    const int stride = gridDim.x * blockDim.x;
    const int Kc32 = K / 32;
    for (int t = blockIdx.x * blockDim.x + threadIdx.x; t < nfrag; t += stride) {
        const int l = t & 63;
        const int rest = t >> 6;
        const int k32 = rest % Kc32;
        const int c32 = rest / Kc32;
        const int col = c32 * 32 + (l & 31);
        const int kb = k32 * 32 + (l >> 5) * 16;
        const int* src = w + (int64_t)col * K + kb;
        int4 out;
        int* op = (int*)&out;
#pragma unroll
        for (int j = 0; j < 4; j++) {
            int4 v = *(const int4*)(src + 4 * j);
            op[j] = (v.x & 255) | ((v.y & 255) << 8) | ((v.z & 255) << 16) | ((v.w & 255) << 24);
        }
        q[t] = out;
    }
}

// ---------------- main GEMM: C[i][j] = sum_k A[i][k] * W[j][k] ----------------
// ROUND 7: R1 base structure (best measured: 157us, 2-buffer __syncthreads,
// 256x128 block, 4 waves 2x2, wave tile 128x64) with B REMOVED FROM LDS.
// Cross-round invariant: bank-conflict cost = 4.0 cy per ds_read_b128 in
// EVERY swizzle/geometry tried -> LDS cycles (reads+conflicts+writes ~180k/CU)
// exceed MFMA (149k/CU). Fix = fewer LDS ops, not better schedule:
//  - B-fragments come pre-packed (pack_weight_kernel) and are loaded
//    global->register (L2-resident: B slab per K-step = 256KB).
//  - LDS holds A only: 2 x 16 KiB. Reads -33%, writes -50%, conflicts -33%.
//  - bf is a SINGLE register set (16 VGPR); tile t+1 loads are placed AFTER
//    the MFMA cluster (register WAR orders them), and the barrier's vmcnt
//    drain completes them for free. Keeps arch VGPR <= 128 so arch+acc <= 256
//    preserves 2 waves/SIMD (R5 lesson: >256 total = occupancy collapse).
#define BM 256
#define BN 128
#define BK 64

__global__ __launch_bounds__(256, 2) void gemm_i8_kernel(
    const int8_t* __restrict__ A, const int8_t* __restrict__ W,
    const int* __restrict__ bias, int* __restrict__ C,
    const float* __restrict__ oscale_p, const int* __restrict__ ozp_p,
    int N, int K, int M) {
    __shared__ int8_t lA[2][BM * BK];  // 2 x 16 KiB = 32 KiB total

    const int tid = threadIdx.x;
    const int lane = tid & 63;
    const int w = tid >> 6;   // wave 0..3
    const int wm = w >> 1;    // wave row (0..1), tile rows wm*128
    const int wn = w & 1;     // wave col (0..1), tile cols wn*64

    const int bm = blockIdx.y * BM;
    const int bn = blockIdx.x * BN;

    // --- A staging: lane l -> LDS row (base + l>>2), physical chunk l&3;
    // global source chunk = (l&3) ^ ((row>>1)&3)  [swizzle at the source]
    const int s_sub = lane >> 2;                                  // 0..15
    const int s_col = (((lane & 3) ^ ((s_sub >> 1) & 3))) * 16;   // swizzled col
    const int8_t* gA = A + (int64_t)(bm + w * 64 + s_sub) * K + s_col;
    const int64_t rs = (int64_t)16 * K;   // +16 rows per chunk
    int8_t* lA0 = &lA[0][w * 4096];
    int8_t* lA1 = &lA[1][w * 4096];

    // --- B fragment pointer (fragment-order layout, see pack_weight_kernel)
    const int Kc32 = K >> 5;
    const int8_t* pB = W + ((int64_t)(blockIdx.x * (BN / 32) + wn * 2) * Kc32 * 64 +
                            lane) * 16;
    const int64_t nsoff = (int64_t)Kc32 * 1024;  // +1 c32 (32 cols)

    // --- A fragment identities (A: [m=lane&31][k=(lane>>5)*16+j])
    const int m0 = lane & 31;
    const int rsw = (m0 >> 1) & 3;   // row-swizzle term
    const int chi = lane >> 5;       // k-half chunk contribution

    v16i acc[4][2];
#pragma unroll
    for (int i = 0; i < 4; i++)
#pragma unroll
        for (int j = 0; j < 2; j++)
#pragma unroll
            for (int r = 0; r < 16; r++) acc[i][j][r] = 0;

    v4i bf[2][2];  // [k0 half][ns] — single set, 16 VGPR

    // prologue: stage A tile 0 into buf 0; load B frags for tile 0
    {
        async_load16(gA, lA0);
        async_load16(gA + rs, lA0 + 1024);
        async_load16(gA + 2 * rs, lA0 + 2048);
        async_load16(gA + 3 * rs, lA0 + 3072);
        gA += BK;
        bf[0][0] = *(const v4i*)(pB);
        bf[1][0] = *(const v4i*)(pB + 1024);
        bf[0][1] = *(const v4i*)(pB + nsoff);
        bf[1][1] = *(const v4i*)(pB + nsoff + 1024);
        pB += 2048;
    }

    int cur = 0;
    for (int kt = 0; kt < K; kt += BK) {
        __syncthreads();  // drains vmcnt -> A tile + bf regs ready
        const bool more = (kt + BK < K);
        if (more) {
            int8_t* dA = cur ? lA0 : lA1;
            async_load16(gA, dA);
            async_load16(gA + rs, dA + 1024);
            async_load16(gA + 2 * rs, dA + 2048);
            async_load16(gA + 3 * rs, dA + 3072);
            gA += BK;
        }
        const int8_t* cA = &lA[cur][0];
#pragma unroll
        for (int k0 = 0; k0 < BK; k0 += 32) {
            const int cb = k0 >> 4;  // 0 or 2
            v4i af[4];
#pragma unroll
            for (int ms = 0; ms < 4; ms++)
                af[ms] = *(const v4i*)&cA[(wm * 128 + ms * 32 + m0) * BK +
                                          (((cb + chi) ^ rsw) << 4)];
#pragma unroll
            for (int ms = 0; ms < 4; ms++)
#pragma unroll
                for (int ns = 0; ns < 2; ns++)
                    acc[ms][ns] = __builtin_amdgcn_mfma_i32_32x32x32_i8(
                        af[ms], bf[k0 >> 5][ns], acc[ms][ns], 0, 0, 0);
        }
        // reload bf for tile t+1 AFTER the MFMAs (register WAR keeps order);
        // completion folds into the next barrier's vmcnt drain.
        if (more) {
            bf[0][0] = *(const v4i*)(pB);
            bf[1][0] = *(const v4i*)(pB + 1024);
            bf[0][1] = *(const v4i*)(pB + nsoff);
            bf[1][1] = *(const v4i*)(pB + nsoff + 1024);
            pB += 2048;
        }
        cur ^= 1;
    }

    // --- epilogue: requantize, store int32
    // C/D layout (32x32): col = lane&31, row = (reg&3) + 8*(reg>>2) + 4*(lane>>5)
    const float inv_os = 1.0f / *oscale_p;
    const int ozp = *ozp_p;
    const int rbase = 4 * (lane >> 5);
#pragma unroll
    for (int ns = 0; ns < 2; ns++) {
        const int gn = bn + wn * 64 + ns * 32 + m0;
        const int bv = bias[gn];
#pragma unroll
        for (int ms = 0; ms < 4; ms++) {
            const int gm0 = bm + wm * 128 + ms * 32 + rbase;
            v16i a = acc[ms][ns];
#pragma unroll
            for (int reg = 0; reg < 16; reg++) {
                const int row = (reg & 3) + 8 * (reg >> 2);
                int v = a[reg] + bv;
                int q = (int)rintf((float)v * inv_os) + ozp;
                q = clamp_i8(q);
                C[(int64_t)(gm0 + row) * M + gn] = q;
            }
        }
    }
}

extern "C" void kernel_launch(void* const* d_in, const int* in_sizes, int n_in,
                              void* d_out, int out_size, void* d_ws, size_t ws_size,
                              hipStream_t stream) {
    const float* x = (const float*)d_in[0];
    const int* wgt = (const int*)d_in[1];
    const int* bias = (const int*)d_in[2];
    const float* in_scale = (const float*)d_in[3];
    const int* in_zp = (const int*)d_in[4];
    const float* out_scale = (const float*)d_in[5];
    const int* out_zp = (const int*)d_in[6];

    const int64_t x_elems = (int64_t)in_sizes[0];  // N*K
    const int OUT = in_sizes[2];                   // bias length
    const int K = in_sizes[1] / OUT;               // IN
    const int N = (int)(x_elems / K);

    int8_t* qA = (int8_t*)d_ws;
    int8_t* qW = qA + x_elems;

    {
        int n4 = (int)(x_elems / 4);               // 8.4M float4s
        quant_input_kernel<<<4096, 256, 0, stream>>>(
            (const float4*)x, (int*)qA, in_scale, in_zp, n4);
    }
    {
        int nfrag = (int)(((int64_t)OUT * K) / 16);  // 16B fragments
        pack_weight_kernel<<<2048, 256, 0, stream>>>(
            (const int*)wgt, (int4*)qW, K, nfrag);
    }
    dim3 grid(OUT / BN, N / BM);
    gemm_i8_kernel<<<grid, 256, 0, stream>>>(qA, qW, bias, (int*)d_out,
                                             out_scale, out_zp, N, K, OUT);
}